// Round 5
// baseline (1051.544 us; speedup 1.0000x reference)
//
#include <hip/hip_runtime.h>
#include <hip/hip_bf16.h>
#include <math.h>

#define T_ 4096
#define H_ 1024
#define E_ 8
#define I_ 2048
#define EPS_ 1e-5f
#define LDST 72   // LDS row stride in bf16 elems (144 B, 16B-aligned)

using bf16x8 = __attribute__((ext_vector_type(8))) short;
using f32x4  = __attribute__((ext_vector_type(4))) float;

static __device__ __forceinline__ unsigned short f2bf(float f) {
    union { float f; unsigned int u; } v; v.f = f;
    unsigned int u = v.u;
    u += 0x7fffu + ((u >> 16) & 1u);   // RNE
    return (unsigned short)(u >> 16);
}

// ---------------- Kernel 0: fp32 -> bf16 weight preconvert -----------------
__global__ __launch_bounds__(256) void k_convert(
    const float* __restrict__ src, unsigned short* __restrict__ dst)
{
    size_t i = (size_t)blockIdx.x * 256 + threadIdx.x;
    const float4* s = (const float4*)src + i * 2;
    float4 a = s[0], b = s[1];
    ushort4 lo, hi;
    lo.x = f2bf(a.x); lo.y = f2bf(a.y); lo.z = f2bf(a.z); lo.w = f2bf(a.w);
    hi.x = f2bf(b.x); hi.y = f2bf(b.y); hi.z = f2bf(b.z); hi.w = f2bf(b.w);
    ((ushort4*)dst)[i * 2]     = lo;
    ((ushort4*)dst)[i * 2 + 1] = hi;
}

// ---------------- Kernel 1: RMSNorm + gate logits + top-2 routing ----------
__global__ __launch_bounds__(256) void k_norm_gate(
    const float* __restrict__ x, const float* __restrict__ scale,
    const float* __restrict__ gk, const float* __restrict__ gb,
    unsigned short* __restrict__ normed_bf,
    int* __restrict__ counts, int* __restrict__ tok_list, float* __restrict__ w_list)
{
    int t = blockIdx.x;
    int tid = threadIdx.x;
    int lane = tid & 63, wave = tid >> 6;

    float4 xv = ((const float4*)(x + (size_t)t * H_))[tid];
    float ss = xv.x*xv.x + xv.y*xv.y + xv.z*xv.z + xv.w*xv.w;
    #pragma unroll
    for (int off = 32; off; off >>= 1) ss += __shfl_down(ss, off);

    __shared__ float red[4];
    __shared__ float s_inv;
    if (lane == 0) red[wave] = ss;
    __syncthreads();
    if (tid == 0) {
        float tot = red[0] + red[1] + red[2] + red[3];
        s_inv = 1.0f / sqrtf(tot / (float)H_ + EPS_);
    }
    __syncthreads();
    float inv = s_inv;

    float4 sv = ((const float4*)scale)[tid];
    float nv[4];
    nv[0] = xv.x*inv*sv.x; nv[1] = xv.y*inv*sv.y;
    nv[2] = xv.z*inv*sv.z; nv[3] = xv.w*inv*sv.w;
    ushort4 nb;
    nb.x = f2bf(nv[0]); nb.y = f2bf(nv[1]); nb.z = f2bf(nv[2]); nb.w = f2bf(nv[3]);
    ((ushort4*)(normed_bf + (size_t)t * H_))[tid] = nb;

    float p[E_];
    #pragma unroll
    for (int e = 0; e < E_; e++) p[e] = 0.f;
    int h0 = tid * 4;
    #pragma unroll
    for (int j = 0; j < 4; j++) {
        const float4* g4 = (const float4*)(gk + (size_t)(h0 + j) * E_);
        float4 a = g4[0], b = g4[1];
        float n = nv[j];
        p[0] += n*a.x; p[1] += n*a.y; p[2] += n*a.z; p[3] += n*a.w;
        p[4] += n*b.x; p[5] += n*b.y; p[6] += n*b.z; p[7] += n*b.w;
    }
    __shared__ float pr[E_][4];
    #pragma unroll
    for (int e = 0; e < E_; e++) {
        float v = p[e];
        #pragma unroll
        for (int off = 32; off; off >>= 1) v += __shfl_down(v, off);
        if (lane == 0) pr[e][wave] = v;
    }
    __syncthreads();
    if (tid == 0) {
        float lg[E_];
        #pragma unroll
        for (int e = 0; e < E_; e++)
            lg[e] = pr[e][0] + pr[e][1] + pr[e][2] + pr[e][3] + gb[e];
        int b0 = -1, b1 = -1; float l0 = -1e30f, l1 = -1e30f;
        #pragma unroll
        for (int e = 0; e < E_; e++) {
            if (lg[e] > l0) { l1 = l0; b1 = b0; l0 = lg[e]; b0 = e; }
            else if (lg[e] > l1) { l1 = lg[e]; b1 = e; }
        }
        float e1 = expf(l1 - l0);
        float w0 = 1.f / (1.f + e1);
        float w1 = e1 / (1.f + e1);
        int p0 = atomicAdd(&counts[b0], 1);
        tok_list[b0 * T_ + p0] = t * 2 + 0; w_list[b0 * T_ + p0] = w0;
        int p1 = atomicAdd(&counts[b1], 1);
        tok_list[b1 * T_ + p1] = t * 2 + 1; w_list[b1 * T_ + p1] = w1;
    }
}

// ---------------- Kernel 2: out = x (residual init) ------------------------
__global__ __launch_bounds__(256) void k_init_out(
    const float* __restrict__ x, float* __restrict__ out)
{
    size_t i = (size_t)blockIdx.x * 256 + threadIdx.x;
    ((float4*)out)[i] = ((const float4*)x)[i];
}

// ---------------- Kernel 3: GEMM1 128Mx(64g+64l)x64k + SwiGLU -> act -------
// Wave grid 2x2: wr = M half, wc = 0:gate / 1:linear. Plain ds_write staging
// (LDST=72 pad), verified epilogue exchange from round 2.
template<bool PRE>
__global__ __launch_bounds__(256) void k_mlp1(
    const float* __restrict__ w1f, const unsigned short* __restrict__ w1b,
    const float* __restrict__ b1,
    const unsigned short* __restrict__ normed_bf,
    const int* __restrict__ counts, const int* __restrict__ tok_list,
    unsigned short* __restrict__ act)
{
    int e = blockIdx.z;
    int Ne = counts[e];
    int mt0 = blockIdx.y * 128;
    if (mt0 >= Ne) return;
    int it0 = blockIdx.x * 64;

    int tid = threadIdx.x;
    int w = tid >> 6, lane = tid & 63;
    int quad = lane >> 4, m16 = lane & 15;
    int wr = w >> 1, wc = w & 1;

    __shared__ __align__(16) char smem[36864];
    unsigned short* lA = (unsigned short*)smem;            // 128 x LDST
    unsigned short* lB = (unsigned short*)(smem + 18432);  // 128 x LDST
    __shared__ int ls_tk[128];

    if (tid < 128) {
        int slot = mt0 + tid;
        ls_tk[tid] = (slot < Ne) ? tok_list[e * T_ + slot] : -1;
    }
    __syncthreads();

    // staging: thread -> (row rS, half) ; 64 B (4 x uint4) each for A and B
    int rS = tid >> 1, half = tid & 1;
    int c0 = half * 32;                               // elem offset within row
    int tkS = ls_tk[rS];
    const unsigned short* srcA =
        normed_bf + (size_t)((tkS < 0) ? 0 : (tkS >> 1)) * H_ + c0;
    int featS = (rS < 64) ? (it0 + rS) : (I_ + it0 + (rS - 64));
    const unsigned short* srcB =
        PRE ? (w1b + (size_t)e * 2 * I_ * H_ + (size_t)featS * H_ + c0) : nullptr;
    const float* srcBf =
        PRE ? nullptr : (w1f + (size_t)e * 2 * I_ * H_ + (size_t)featS * H_ + c0);

    f32x4 acc[4][4];
    #pragma unroll
    for (int mi = 0; mi < 4; mi++)
        #pragma unroll
        for (int ni = 0; ni < 4; ni++)
            acc[mi][ni] = (f32x4){0.f, 0.f, 0.f, 0.f};

    for (int kk = 0; kk < H_; kk += 64) {
        // A tile
        {
            const uint4* g = (const uint4*)(srcA + kk);
            #pragma unroll
            for (int q = 0; q < 4; q++) {
                uint4 v = (tkS >= 0) ? g[q] : make_uint4(0u, 0u, 0u, 0u);
                *(uint4*)(&lA[rS * LDST + c0 + q * 8]) = v;
            }
        }
        // B tile
        if (PRE) {
            const uint4* g = (const uint4*)(srcB + kk);
            #pragma unroll
            for (int q = 0; q < 4; q++)
                *(uint4*)(&lB[rS * LDST + c0 + q * 8]) = g[q];
        } else {
            const float* s = srcBf + kk;
            #pragma unroll
            for (int q = 0; q < 4; q++) {
                float4 f0 = ((const float4*)s)[q * 2];
                float4 f1 = ((const float4*)s)[q * 2 + 1];
                ushort4 u;
                u.x = f2bf(f0.x); u.y = f2bf(f0.y); u.z = f2bf(f0.z); u.w = f2bf(f0.w);
                ushort4 u2;
                u2.x = f2bf(f1.x); u2.y = f2bf(f1.y); u2.z = f2bf(f1.z); u2.w = f2bf(f1.w);
                *(ushort4*)(&lB[rS * LDST + c0 + q * 8])     = u;
                *(ushort4*)(&lB[rS * LDST + c0 + q * 8 + 4]) = u2;
            }
        }
        __syncthreads();
        #pragma unroll
        for (int ks = 0; ks < 64; ks += 32) {
            const unsigned short* pA = &lA[(wr * 64 + m16) * LDST + ks + quad * 8];
            const unsigned short* pB = &lB[(wc * 64 + m16) * LDST + ks + quad * 8];
            bf16x8 av[4], bv[4];
            #pragma unroll
            for (int i4 = 0; i4 < 4; i4++) av[i4] = *(const bf16x8*)(pA + i4 * 16 * LDST);
            #pragma unroll
            for (int i4 = 0; i4 < 4; i4++) bv[i4] = *(const bf16x8*)(pB + i4 * 16 * LDST);
            #pragma unroll
            for (int mi = 0; mi < 4; mi++)
                #pragma unroll
                for (int ni = 0; ni < 4; ni++)
                    acc[mi][ni] = __builtin_amdgcn_mfma_f32_16x16x32_bf16(
                        av[mi], bv[ni], acc[mi][ni], 0, 0, 0);
        }
        __syncthreads();
    }

    // ---- epilogue: balanced gate/linear exchange through LDS (r2-verified) ----
    float* exL = (float*)smem;          // [2][2][4][4][68]
    float* exG = exL + 4352;
    const float* b1g = b1 + (size_t)e * 2 * I_;
    const float* b1l = b1g + I_;

    #pragma unroll
    for (int mih = 0; mih < 2; mih++) {
        #pragma unroll
        for (int ni = 0; ni < 4; ni++) {
            #pragma unroll
            for (int reg = 0; reg < 4; reg++) {
                int ix = (((wr * 2 + mih) * 4 + ni) * 4 + reg) * 68 + quad * 17 + m16;
                if (wc == 1) exL[ix] = acc[mih][ni][reg];       // linear sends lo half
                else         exG[ix] = acc[2 + mih][ni][reg];   // gate sends hi half
            }
        }
    }
    __syncthreads();

    int miBase = (wc == 0) ? 0 : 2;
    #pragma unroll
    for (int mih = 0; mih < 2; mih++) {
        int mi = miBase + mih;
        #pragma unroll
        for (int reg = 0; reg < 4; reg++) {
            int row = wr * 64 + mi * 16 + quad * 4 + reg;
            int tk = ls_tk[row];
            if (tk < 0) continue;
            #pragma unroll
            for (int ni = 0; ni < 4; ni++) {
                int i = it0 + ni * 16 + m16;
                int ix = (((wr * 2 + mih) * 4 + ni) * 4 + reg) * 68 + quad * 17 + m16;
                float g, l;
                if (wc == 0) { g = acc[mi][ni][reg]; l = exL[ix]; }
                else         { g = exG[ix];          l = acc[mi][ni][reg]; }
                g += b1g[i]; l += b1l[i];
                g = fminf(g, 7.f);
                l = fminf(fmaxf(l, -7.f), 7.f);
                float sw = g / (1.f + expf(-1.702f * g));
                act[(size_t)tk * I_ + i] = f2bf(sw * (l + 1.f));
            }
        }
    }
}

// ---------------- Kernel 4: GEMM2 128x128x64, weighted scatter-add ---------
template<bool PRE>
__global__ __launch_bounds__(256) void k_mlp2(
    const float* __restrict__ w2f, const unsigned short* __restrict__ w2b,
    const float* __restrict__ b2,
    const unsigned short* __restrict__ act,
    const int* __restrict__ counts, const int* __restrict__ tok_list,
    const float* __restrict__ w_list,
    float* __restrict__ out)
{
    int e = blockIdx.z;
    int Ne = counts[e];
    int mt0 = blockIdx.y * 128;
    if (mt0 >= Ne) return;
    int ht0 = blockIdx.x * 128;

    int tid = threadIdx.x;
    int w = tid >> 6, lane = tid & 63;
    int quad = lane >> 4, m16 = lane & 15;
    int wr = w >> 1, wc = w & 1;

    __shared__ __align__(16) char smem[36864];
    unsigned short* lA = (unsigned short*)smem;
    unsigned short* lB = (unsigned short*)(smem + 18432);
    __shared__ int ls_tk[128];
    __shared__ float ls_w[128];

    if (tid < 128) {
        int slot = mt0 + tid;
        ls_tk[tid] = (slot < Ne) ? tok_list[e * T_ + slot] : -1;
        ls_w[tid]  = (slot < Ne) ? w_list[e * T_ + slot] : 0.f;
    }
    __syncthreads();

    int rS = tid >> 1, half = tid & 1;
    int c0 = half * 32;
    int tkS = ls_tk[rS];
    const unsigned short* srcA =
        act + (size_t)((tkS < 0) ? 0 : tkS) * I_ + c0;
    const unsigned short* srcB =
        PRE ? (w2b + (size_t)e * H_ * I_ + (size_t)(ht0 + rS) * I_ + c0) : nullptr;
    const float* srcBf =
        PRE ? nullptr : (w2f + (size_t)e * H_ * I_ + (size_t)(ht0 + rS) * I_ + c0);

    f32x4 acc[4][4];
    #pragma unroll
    for (int mi = 0; mi < 4; mi++)
        #pragma unroll
        for (int ni = 0; ni < 4; ni++)
            acc[mi][ni] = (f32x4){0.f, 0.f, 0.f, 0.f};

    for (int kk = 0; kk < I_; kk += 64) {
        {
            const uint4* g = (const uint4*)(srcA + kk);
            #pragma unroll
            for (int q = 0; q < 4; q++) {
                uint4 v = (tkS >= 0) ? g[q] : make_uint4(0u, 0u, 0u, 0u);
                *(uint4*)(&lA[rS * LDST + c0 + q * 8]) = v;
            }
        }
        if (PRE) {
            const uint4* g = (const uint4*)(srcB + kk);
            #pragma unroll
            for (int q = 0; q < 4; q++)
                *(uint4*)(&lB[rS * LDST + c0 + q * 8]) = g[q];
        } else {
            const float* s = srcBf + kk;
            #pragma unroll
            for (int q = 0; q < 4; q++) {
                float4 f0 = ((const float4*)s)[q * 2];
                float4 f1 = ((const float4*)s)[q * 2 + 1];
                ushort4 u;
                u.x = f2bf(f0.x); u.y = f2bf(f0.y); u.z = f2bf(f0.z); u.w = f2bf(f0.w);
                ushort4 u2;
                u2.x = f2bf(f1.x); u2.y = f2bf(f1.y); u2.z = f2bf(f1.z); u2.w = f2bf(f1.w);
                *(ushort4*)(&lB[rS * LDST + c0 + q * 8])     = u;
                *(ushort4*)(&lB[rS * LDST + c0 + q * 8 + 4]) = u2;
            }
        }
        __syncthreads();
        #pragma unroll
        for (int ks = 0; ks < 64; ks += 32) {
            const unsigned short* pA = &lA[(wr * 64 + m16) * LDST + ks + quad * 8];
            const unsigned short* pB = &lB[(wc * 64 + m16) * LDST + ks + quad * 8];
            bf16x8 av[4], bv[4];
            #pragma unroll
            for (int i4 = 0; i4 < 4; i4++) av[i4] = *(const bf16x8*)(pA + i4 * 16 * LDST);
            #pragma unroll
            for (int i4 = 0; i4 < 4; i4++) bv[i4] = *(const bf16x8*)(pB + i4 * 16 * LDST);
            #pragma unroll
            for (int mi = 0; mi < 4; mi++)
                #pragma unroll
                for (int ni = 0; ni < 4; ni++)
                    acc[mi][ni] = __builtin_amdgcn_mfma_f32_16x16x32_bf16(
                        av[mi], bv[ni], acc[mi][ni], 0, 0, 0);
        }
        __syncthreads();
    }

    const float* b2e = b2 + (size_t)e * H_;
    #pragma unroll
    for (int mi = 0; mi < 4; mi++) {
        #pragma unroll
        for (int reg = 0; reg < 4; reg++) {
            int row = wr * 64 + mi * 16 + quad * 4 + reg;
            int tk = ls_tk[row];
            if (tk < 0) continue;
            int t = tk >> 1;
            float wgt = ls_w[row];
            #pragma unroll
            for (int ni = 0; ni < 4; ni++) {
                int h = ht0 + wc * 64 + ni * 16 + m16;
                float v = acc[mi][ni][reg] + b2e[h];
                atomicAdd(&out[(size_t)t * H_ + h], wgt * v);
            }
        }
    }
}

// ---------------- launcher -------------------------------------------------
extern "C" void kernel_launch(void* const* d_in, const int* in_sizes, int n_in,
                              void* d_out, int out_size, void* d_ws, size_t ws_size,
                              hipStream_t stream) {
    const float* x     = (const float*)d_in[0];
    const float* scale = (const float*)d_in[1];
    const float* gk    = (const float*)d_in[2];
    const float* gb    = (const float*)d_in[3];
    const float* w1    = (const float*)d_in[4];
    const float* b1    = (const float*)d_in[5];
    const float* w2    = (const float*)d_in[6];
    const float* b2    = (const float*)d_in[7];
    float* out = (float*)d_out;

    char* ws = (char*)d_ws;
    const size_t MB = 1024 * 1024;
    bool pre = ws_size >= (size_t)138 * MB;

    unsigned short* normed_bf = (unsigned short*)ws;                    // 8 MB
    unsigned short* act       = (unsigned short*)(ws + 8 * MB);         // 32 MB
    unsigned short* w1b = nullptr;
    unsigned short* w2b = nullptr;
    char* ctl;
    if (pre) {
        w1b = (unsigned short*)(ws + 40 * MB);    // 64 MB
        w2b = (unsigned short*)(ws + 104 * MB);   // 32 MB
        ctl = ws + 136 * MB;
    } else {
        ctl = ws + 40 * MB;
    }
    int*   counts   = (int*)ctl;
    int*   tok_list = (int*)(ctl + 256);
    float* w_list   = (float*)(ctl + 256 + (size_t)E_ * T_ * 4);

    hipMemsetAsync(counts, 0, E_ * sizeof(int), stream);

    k_norm_gate<<<dim3(T_), dim3(256), 0, stream>>>(x, scale, gk, gb,
                                                    normed_bf, counts, tok_list, w_list);
    if (pre) {
        k_convert<<<dim3((E_ * 2 * I_ * H_) / (256 * 8)), dim3(256), 0, stream>>>(w1, w1b);
        k_convert<<<dim3((E_ * H_ * I_) / (256 * 8)), dim3(256), 0, stream>>>(w2, w2b);
    }
    k_init_out<<<dim3(T_ * H_ / (256 * 4)), dim3(256), 0, stream>>>(x, out);

    if (pre) {
        k_mlp1<true><<<dim3(I_ / 64, T_ / 128, E_), dim3(256), 0, stream>>>(
            nullptr, w1b, b1, normed_bf, counts, tok_list, act);
        k_mlp2<true><<<dim3(H_ / 128, T_ / 128, E_), dim3(256), 0, stream>>>(
            nullptr, w2b, b2, act, counts, tok_list, w_list, out);
    } else {
        k_mlp1<false><<<dim3(I_ / 64, T_ / 128, E_), dim3(256), 0, stream>>>(
            w1, nullptr, b1, normed_bf, counts, tok_list, act);
        k_mlp2<false><<<dim3(H_ / 128, T_ / 128, E_), dim3(256), 0, stream>>>(
            w2, nullptr, b2, act, counts, tok_list, w_list, out);
    }
}

// Round 6
// 603.885 us; speedup vs baseline: 1.7413x; 1.7413x over previous
//
#include <hip/hip_runtime.h>
#include <hip/hip_bf16.h>
#include <math.h>

#define T_ 4096
#define H_ 1024
#define E_ 8
#define I_ 2048
#define EPS_ 1e-5f
#define LDST 72   // LDS row stride in bf16 elems (144 B, 16B-aligned)

using bf16x8 = __attribute__((ext_vector_type(8))) short;
using f32x4  = __attribute__((ext_vector_type(4))) float;

static __device__ __forceinline__ unsigned short f2bf(float f) {
    union { float f; unsigned int u; } v; v.f = f;
    unsigned int u = v.u;
    u += 0x7fffu + ((u >> 16) & 1u);   // RNE
    return (unsigned short)(u >> 16);
}

// ---------------- Kernel 0: fp32 -> bf16 weight preconvert -----------------
__global__ __launch_bounds__(256) void k_convert(
    const float* __restrict__ src, unsigned short* __restrict__ dst)
{
    size_t i = (size_t)blockIdx.x * 256 + threadIdx.x;
    const float4* s = (const float4*)src + i * 2;
    float4 a = s[0], b = s[1];
    ushort4 lo, hi;
    lo.x = f2bf(a.x); lo.y = f2bf(a.y); lo.z = f2bf(a.z); lo.w = f2bf(a.w);
    hi.x = f2bf(b.x); hi.y = f2bf(b.y); hi.z = f2bf(b.z); hi.w = f2bf(b.w);
    ((ushort4*)dst)[i * 2]     = lo;
    ((ushort4*)dst)[i * 2 + 1] = hi;
}

// ---------------- Kernel 1: RMSNorm + gate logits + top-2 routing ----------
__global__ __launch_bounds__(256) void k_norm_gate(
    const float* __restrict__ x, const float* __restrict__ scale,
    const float* __restrict__ gk, const float* __restrict__ gb,
    unsigned short* __restrict__ normed_bf,
    int* __restrict__ counts, int* __restrict__ tok_list, float* __restrict__ w_list)
{
    int t = blockIdx.x;
    int tid = threadIdx.x;
    int lane = tid & 63, wave = tid >> 6;

    float4 xv = ((const float4*)(x + (size_t)t * H_))[tid];
    float ss = xv.x*xv.x + xv.y*xv.y + xv.z*xv.z + xv.w*xv.w;
    #pragma unroll
    for (int off = 32; off; off >>= 1) ss += __shfl_down(ss, off);

    __shared__ float red[4];
    __shared__ float s_inv;
    if (lane == 0) red[wave] = ss;
    __syncthreads();
    if (tid == 0) {
        float tot = red[0] + red[1] + red[2] + red[3];
        s_inv = 1.0f / sqrtf(tot / (float)H_ + EPS_);
    }
    __syncthreads();
    float inv = s_inv;

    float4 sv = ((const float4*)scale)[tid];
    float nv[4];
    nv[0] = xv.x*inv*sv.x; nv[1] = xv.y*inv*sv.y;
    nv[2] = xv.z*inv*sv.z; nv[3] = xv.w*inv*sv.w;
    ushort4 nb;
    nb.x = f2bf(nv[0]); nb.y = f2bf(nv[1]); nb.z = f2bf(nv[2]); nb.w = f2bf(nv[3]);
    ((ushort4*)(normed_bf + (size_t)t * H_))[tid] = nb;

    float p[E_];
    #pragma unroll
    for (int e = 0; e < E_; e++) p[e] = 0.f;
    int h0 = tid * 4;
    #pragma unroll
    for (int j = 0; j < 4; j++) {
        const float4* g4 = (const float4*)(gk + (size_t)(h0 + j) * E_);
        float4 a = g4[0], b = g4[1];
        float n = nv[j];
        p[0] += n*a.x; p[1] += n*a.y; p[2] += n*a.z; p[3] += n*a.w;
        p[4] += n*b.x; p[5] += n*b.y; p[6] += n*b.z; p[7] += n*b.w;
    }
    __shared__ float pr[E_][4];
    #pragma unroll
    for (int e = 0; e < E_; e++) {
        float v = p[e];
        #pragma unroll
        for (int off = 32; off; off >>= 1) v += __shfl_down(v, off);
        if (lane == 0) pr[e][wave] = v;
    }
    __syncthreads();
    if (tid == 0) {
        float lg[E_];
        #pragma unroll
        for (int e = 0; e < E_; e++)
            lg[e] = pr[e][0] + pr[e][1] + pr[e][2] + pr[e][3] + gb[e];
        int b0 = -1, b1 = -1; float l0 = -1e30f, l1 = -1e30f;
        #pragma unroll
        for (int e = 0; e < E_; e++) {
            if (lg[e] > l0) { l1 = l0; b1 = b0; l0 = lg[e]; b0 = e; }
            else if (lg[e] > l1) { l1 = lg[e]; b1 = e; }
        }
        float e1 = expf(l1 - l0);
        float w0 = 1.f / (1.f + e1);
        float w1 = e1 / (1.f + e1);
        int p0 = atomicAdd(&counts[b0], 1);
        tok_list[b0 * T_ + p0] = t * 2 + 0; w_list[b0 * T_ + p0] = w0;
        int p1 = atomicAdd(&counts[b1], 1);
        tok_list[b1 * T_ + p1] = t * 2 + 1; w_list[b1 * T_ + p1] = w1;
    }
}

// ---------------- Kernel 2: out = x (residual init) ------------------------
__global__ __launch_bounds__(256) void k_init_out(
    const float* __restrict__ x, float* __restrict__ out)
{
    size_t i = (size_t)blockIdx.x * 256 + threadIdx.x;
    ((float4*)out)[i] = ((const float4*)x)[i];
}

// ---------------- Kernel 3: GEMM1 (normed x W1^T) + SwiGLU -> act ----------
// Block tile 64 slots x 64 i (gate+linear). Wave grid 2x2: wave (wr,wc) owns
// M [wr*32,+32) x i-cols [wc*32,+32) for BOTH gate and linear -> 6 ds_reads
// per 8 MFMA (r4 was 9:8). Staging identical to round 4 (proven clean).
template<bool PRE>
__global__ __launch_bounds__(256) void k_mlp1(
    const float* __restrict__ w1f, const unsigned short* __restrict__ w1b,
    const float* __restrict__ b1,
    const unsigned short* __restrict__ normed_bf,
    const int* __restrict__ counts, const int* __restrict__ tok_list,
    unsigned short* __restrict__ act)
{
    int e = blockIdx.z;
    int Ne = counts[e];
    int mt0 = blockIdx.y * 64;
    if (mt0 >= Ne) return;
    int it0 = blockIdx.x * 64;
    int tid = threadIdx.x;
    int lane = tid & 63, w = tid >> 6;
    int quad = lane >> 4, m16 = lane & 15;
    int wr = w >> 1, wc = w & 1;

    __shared__ unsigned short lA[64 * LDST];
    __shared__ unsigned short lBg[64 * LDST];
    __shared__ unsigned short lBl[64 * LDST];
    __shared__ int ls_tk[64];

    if (tid < 64) {
        int slot = mt0 + tid;
        ls_tk[tid] = (slot < Ne) ? tok_list[e * T_ + slot] : -1;
    }
    __syncthreads();

    f32x4 accg[2][2], accl[2][2];
    #pragma unroll
    for (int mi = 0; mi < 2; mi++)
        #pragma unroll
        for (int ni = 0; ni < 2; ni++) {
            accg[mi][ni] = (f32x4){0.f, 0.f, 0.f, 0.f};
            accl[mi][ni] = (f32x4){0.f, 0.f, 0.f, 0.f};
        }

    const size_t w1base = (size_t)e * 2 * I_ * H_;
    int rA = tid >> 3, sgA = tid & 7;      // A: 8 threads/row, 16B each
    int nB = tid >> 2, sgB = tid & 3;      // B: 4 threads/row, 16 elems each

    for (int kk = 0; kk < H_; kk += 64) {
        #pragma unroll
        for (int rr = 0; rr < 64; rr += 32) {
            int r = rA + rr;
            int tk = ls_tk[r];
            uint4 v = make_uint4(0u, 0u, 0u, 0u);
            if (tk >= 0)
                v = *(const uint4*)(normed_bf + (size_t)(tk >> 1) * H_ + kk + sgA * 8);
            *(uint4*)(&lA[r * LDST + sgA * 8]) = v;
        }
        if (PRE) {
            const unsigned short* srcg = w1b + w1base + (size_t)(it0 + nB) * H_ + kk + sgB * 16;
            const unsigned short* srcl = srcg + (size_t)I_ * H_;
            *(uint4*)(&lBg[nB * LDST + sgB * 16])     = ((const uint4*)srcg)[0];
            *(uint4*)(&lBg[nB * LDST + sgB * 16 + 8]) = ((const uint4*)srcg)[1];
            *(uint4*)(&lBl[nB * LDST + sgB * 16])     = ((const uint4*)srcl)[0];
            *(uint4*)(&lBl[nB * LDST + sgB * 16 + 8]) = ((const uint4*)srcl)[1];
        } else {
            const float* srcg = w1f + w1base + (size_t)(it0 + nB) * H_ + kk + sgB * 16;
            const float* srcl = srcg + (size_t)I_ * H_;
            unsigned short tg[16], tl[16];
            #pragma unroll
            for (int q = 0; q < 4; q++) {
                float4 fg = ((const float4*)srcg)[q];
                float4 fl = ((const float4*)srcl)[q];
                tg[q*4+0] = f2bf(fg.x); tg[q*4+1] = f2bf(fg.y);
                tg[q*4+2] = f2bf(fg.z); tg[q*4+3] = f2bf(fg.w);
                tl[q*4+0] = f2bf(fl.x); tl[q*4+1] = f2bf(fl.y);
                tl[q*4+2] = f2bf(fl.z); tl[q*4+3] = f2bf(fl.w);
            }
            *(uint4*)(&lBg[nB * LDST + sgB * 16])     = *(uint4*)(&tg[0]);
            *(uint4*)(&lBg[nB * LDST + sgB * 16 + 8]) = *(uint4*)(&tg[8]);
            *(uint4*)(&lBl[nB * LDST + sgB * 16])     = *(uint4*)(&tl[0]);
            *(uint4*)(&lBl[nB * LDST + sgB * 16 + 8]) = *(uint4*)(&tl[8]);
        }
        __syncthreads();
        #pragma unroll
        for (int ks = 0; ks < 64; ks += 32) {
            bf16x8 af[2], bg[2], bl[2];
            #pragma unroll
            for (int mi = 0; mi < 2; mi++)
                af[mi] = *(const bf16x8*)(&lA[(wr * 32 + mi * 16 + m16) * LDST + ks + quad * 8]);
            #pragma unroll
            for (int ni = 0; ni < 2; ni++) {
                bg[ni] = *(const bf16x8*)(&lBg[(wc * 32 + ni * 16 + m16) * LDST + ks + quad * 8]);
                bl[ni] = *(const bf16x8*)(&lBl[(wc * 32 + ni * 16 + m16) * LDST + ks + quad * 8]);
            }
            #pragma unroll
            for (int mi = 0; mi < 2; mi++)
                #pragma unroll
                for (int ni = 0; ni < 2; ni++) {
                    accg[mi][ni] = __builtin_amdgcn_mfma_f32_16x16x32_bf16(
                        af[mi], bg[ni], accg[mi][ni], 0, 0, 0);
                    accl[mi][ni] = __builtin_amdgcn_mfma_f32_16x16x32_bf16(
                        af[mi], bl[ni], accl[mi][ni], 0, 0, 0);
                }
        }
        __syncthreads();
    }

    const float* b1g = b1 + (size_t)e * 2 * I_;
    const float* b1l = b1g + I_;
    #pragma unroll
    for (int mi = 0; mi < 2; mi++) {
        #pragma unroll
        for (int reg = 0; reg < 4; reg++) {
            int row = wr * 32 + mi * 16 + quad * 4 + reg;
            int tk = ls_tk[row];
            if (tk < 0) continue;
            #pragma unroll
            for (int ni = 0; ni < 2; ni++) {
                int i = it0 + wc * 32 + ni * 16 + m16;
                float g = accg[mi][ni][reg] + b1g[i];
                float l = accl[mi][ni][reg] + b1l[i];
                g = fminf(g, 7.f);
                l = fminf(fmaxf(l, -7.f), 7.f);
                float sw = g / (1.f + expf(-1.702f * g));
                act[(size_t)tk * I_ + i] = f2bf(sw * (l + 1.f));
            }
        }
    }
}

// ---------------- Kernel 4: GEMM2 (act x W2^T) 64Mx128N, scatter-add -------
// Wave (wr,wc): M [wr*32,+32) x h-cols [wc*64,+64); 6 ds_reads per 8 MFMA.
template<bool PRE>
__global__ __launch_bounds__(256) void k_mlp2(
    const float* __restrict__ w2f, const unsigned short* __restrict__ w2b,
    const float* __restrict__ b2,
    const unsigned short* __restrict__ act,
    const int* __restrict__ counts, const int* __restrict__ tok_list,
    const float* __restrict__ w_list,
    float* __restrict__ out)
{
    int e = blockIdx.z;
    int Ne = counts[e];
    int mt0 = blockIdx.y * 64;
    if (mt0 >= Ne) return;
    int ht0 = blockIdx.x * 128;
    int tid = threadIdx.x;
    int lane = tid & 63, w = tid >> 6;
    int quad = lane >> 4, m16 = lane & 15;
    int wr = w >> 1, wc = w & 1;

    __shared__ unsigned short lA[64 * LDST];
    __shared__ unsigned short lB[128 * LDST];
    __shared__ int ls_tk[64];
    __shared__ float ls_w[64];

    if (tid < 64) {
        int slot = mt0 + tid;
        ls_tk[tid] = (slot < Ne) ? tok_list[e * T_ + slot] : -1;
        ls_w[tid]  = (slot < Ne) ? w_list[e * T_ + slot] : 0.f;
    }
    __syncthreads();

    f32x4 acc[2][4];
    #pragma unroll
    for (int mi = 0; mi < 2; mi++)
        #pragma unroll
        for (int ni = 0; ni < 4; ni++)
            acc[mi][ni] = (f32x4){0.f, 0.f, 0.f, 0.f};

    const size_t w2base = (size_t)e * H_ * I_;
    int rA = tid >> 3, sgA = tid & 7;
    int nB = tid >> 2, sgB = tid & 3;

    for (int kk = 0; kk < I_; kk += 64) {
        #pragma unroll
        for (int rr = 0; rr < 64; rr += 32) {
            int r = rA + rr;
            int tk = ls_tk[r];
            uint4 v = make_uint4(0u, 0u, 0u, 0u);
            if (tk >= 0)
                v = *(const uint4*)(act + (size_t)tk * I_ + kk + sgA * 8);
            *(uint4*)(&lA[r * LDST + sgA * 8]) = v;
        }
        #pragma unroll
        for (int rr = 0; rr < 128; rr += 64) {
            int r = nB + rr;
            if (PRE) {
                const unsigned short* src = w2b + w2base + (size_t)(ht0 + r) * I_ + kk + sgB * 16;
                *(uint4*)(&lB[r * LDST + sgB * 16])     = ((const uint4*)src)[0];
                *(uint4*)(&lB[r * LDST + sgB * 16 + 8]) = ((const uint4*)src)[1];
            } else {
                const float* src = w2f + w2base + (size_t)(ht0 + r) * I_ + kk + sgB * 16;
                unsigned short tb[16];
                #pragma unroll
                for (int q = 0; q < 4; q++) {
                    float4 f4 = ((const float4*)src)[q];
                    tb[q*4+0] = f2bf(f4.x); tb[q*4+1] = f2bf(f4.y);
                    tb[q*4+2] = f2bf(f4.z); tb[q*4+3] = f2bf(f4.w);
                }
                *(uint4*)(&lB[r * LDST + sgB * 16])     = *(uint4*)(&tb[0]);
                *(uint4*)(&lB[r * LDST + sgB * 16 + 8]) = *(uint4*)(&tb[8]);
            }
        }
        __syncthreads();
        #pragma unroll
        for (int ks = 0; ks < 64; ks += 32) {
            bf16x8 af[2], bf[4];
            #pragma unroll
            for (int mi = 0; mi < 2; mi++)
                af[mi] = *(const bf16x8*)(&lA[(wr * 32 + mi * 16 + m16) * LDST + ks + quad * 8]);
            #pragma unroll
            for (int ni = 0; ni < 4; ni++)
                bf[ni] = *(const bf16x8*)(&lB[(wc * 64 + ni * 16 + m16) * LDST + ks + quad * 8]);
            #pragma unroll
            for (int mi = 0; mi < 2; mi++)
                #pragma unroll
                for (int ni = 0; ni < 4; ni++)
                    acc[mi][ni] = __builtin_amdgcn_mfma_f32_16x16x32_bf16(
                        af[mi], bf[ni], acc[mi][ni], 0, 0, 0);
        }
        __syncthreads();
    }

    const float* b2e = b2 + (size_t)e * H_;
    #pragma unroll
    for (int mi = 0; mi < 2; mi++) {
        #pragma unroll
        for (int reg = 0; reg < 4; reg++) {
            int row = wr * 32 + mi * 16 + quad * 4 + reg;
            int tk = ls_tk[row];
            if (tk < 0) continue;
            int t = tk >> 1;
            float wgt = ls_w[row];
            #pragma unroll
            for (int ni = 0; ni < 4; ni++) {
                int h = ht0 + wc * 64 + ni * 16 + m16;
                float v = acc[mi][ni][reg] + b2e[h];
                atomicAdd(&out[(size_t)t * H_ + h], wgt * v);
            }
        }
    }
}

// ---------------- launcher -------------------------------------------------
extern "C" void kernel_launch(void* const* d_in, const int* in_sizes, int n_in,
                              void* d_out, int out_size, void* d_ws, size_t ws_size,
                              hipStream_t stream) {
    const float* x     = (const float*)d_in[0];
    const float* scale = (const float*)d_in[1];
    const float* gk    = (const float*)d_in[2];
    const float* gb    = (const float*)d_in[3];
    const float* w1    = (const float*)d_in[4];
    const float* b1    = (const float*)d_in[5];
    const float* w2    = (const float*)d_in[6];
    const float* b2    = (const float*)d_in[7];
    float* out = (float*)d_out;

    char* ws = (char*)d_ws;
    const size_t MB = 1024 * 1024;
    bool pre = ws_size >= (size_t)138 * MB;

    unsigned short* normed_bf = (unsigned short*)ws;                    // 8 MB
    unsigned short* act       = (unsigned short*)(ws + 8 * MB);         // 32 MB
    unsigned short* w1b = nullptr;
    unsigned short* w2b = nullptr;
    char* ctl;
    if (pre) {
        w1b = (unsigned short*)(ws + 40 * MB);    // 64 MB
        w2b = (unsigned short*)(ws + 104 * MB);   // 32 MB
        ctl = ws + 136 * MB;
    } else {
        ctl = ws + 40 * MB;
    }
    int*   counts   = (int*)ctl;
    int*   tok_list = (int*)(ctl + 256);
    float* w_list   = (float*)(ctl + 256 + (size_t)E_ * T_ * 4);

    hipMemsetAsync(counts, 0, E_ * sizeof(int), stream);

    k_norm_gate<<<dim3(T_), dim3(256), 0, stream>>>(x, scale, gk, gb,
                                                    normed_bf, counts, tok_list, w_list);
    if (pre) {
        k_convert<<<dim3((E_ * 2 * I_ * H_) / (256 * 8)), dim3(256), 0, stream>>>(w1, w1b);
        k_convert<<<dim3((E_ * H_ * I_) / (256 * 8)), dim3(256), 0, stream>>>(w2, w2b);
    }
    k_init_out<<<dim3(T_ * H_ / (256 * 4)), dim3(256), 0, stream>>>(x, out);

    if (pre) {
        k_mlp1<true><<<dim3(I_ / 64, T_ / 64, E_), dim3(256), 0, stream>>>(
            nullptr, w1b, b1, normed_bf, counts, tok_list, act);
        k_mlp2<true><<<dim3(H_ / 128, T_ / 64, E_), dim3(256), 0, stream>>>(
            nullptr, w2b, b2, act, counts, tok_list, w_list, out);
    } else {
        k_mlp1<false><<<dim3(I_ / 64, T_ / 64, E_), dim3(256), 0, stream>>>(
            w1, nullptr, b1, normed_bf, counts, tok_list, act);
        k_mlp2<false><<<dim3(H_ / 128, T_ / 64, E_), dim3(256), 0, stream>>>(
            w2, nullptr, b2, act, counts, tok_list, w_list, out);
    }
}

// Round 7
// 599.804 us; speedup vs baseline: 1.7531x; 1.0068x over previous
//
#include <hip/hip_runtime.h>
#include <hip/hip_bf16.h>
#include <math.h>

#define T_ 4096
#define H_ 1024
#define E_ 8
#define I_ 2048
#define EPS_ 1e-5f
#define LDST 72   // LDS row stride in bf16 elems (144 B, 16B-aligned)

using bf16x8 = __attribute__((ext_vector_type(8))) short;
using f32x4  = __attribute__((ext_vector_type(4))) float;

static __device__ __forceinline__ unsigned short f2bf(float f) {
    union { float f; unsigned int u; } v; v.f = f;
    unsigned int u = v.u;
    u += 0x7fffu + ((u >> 16) & 1u);   // RNE
    return (unsigned short)(u >> 16);
}

// ---------------- Kernel 0: fp32 -> bf16 weight preconvert -----------------
__global__ __launch_bounds__(256) void k_convert(
    const float* __restrict__ src, unsigned short* __restrict__ dst)
{
    size_t i = (size_t)blockIdx.x * 256 + threadIdx.x;
    const float4* s = (const float4*)src + i * 2;
    float4 a = s[0], b = s[1];
    ushort4 lo, hi;
    lo.x = f2bf(a.x); lo.y = f2bf(a.y); lo.z = f2bf(a.z); lo.w = f2bf(a.w);
    hi.x = f2bf(b.x); hi.y = f2bf(b.y); hi.z = f2bf(b.z); hi.w = f2bf(b.w);
    ((ushort4*)dst)[i * 2]     = lo;
    ((ushort4*)dst)[i * 2 + 1] = hi;
}

// ---------------- Kernel 1: RMSNorm + gating, one wave per token -----------
// No __syncthreads: wave-local shfl_xor butterflies; lane 0 does top-2.
__global__ __launch_bounds__(256) void k_norm_gate(
    const float* __restrict__ x, const float* __restrict__ scale,
    const float* __restrict__ gk, const float* __restrict__ gb,
    unsigned short* __restrict__ normed_bf,
    int* __restrict__ counts, int* __restrict__ tok_list, float* __restrict__ w_list)
{
    int tid = threadIdx.x;
    int wave = tid >> 6, lane = tid & 63;
    int t = blockIdx.x * 4 + wave;
    const float* xr = x + (size_t)t * H_;
    int h0 = lane * 16;

    float4 xv[4], sv[4];
    #pragma unroll
    for (int c = 0; c < 4; c++) {
        xv[c] = *(const float4*)(xr + h0 + c * 4);
        sv[c] = *(const float4*)(scale + h0 + c * 4);
    }
    float ss = 0.f;
    #pragma unroll
    for (int c = 0; c < 4; c++)
        ss += xv[c].x*xv[c].x + xv[c].y*xv[c].y + xv[c].z*xv[c].z + xv[c].w*xv[c].w;
    #pragma unroll
    for (int off = 32; off; off >>= 1) ss += __shfl_xor(ss, off);
    float inv = 1.0f / sqrtf(ss / (float)H_ + EPS_);

    float nv[16];
    #pragma unroll
    for (int c = 0; c < 4; c++) {
        nv[c*4+0] = xv[c].x * inv * sv[c].x;
        nv[c*4+1] = xv[c].y * inv * sv[c].y;
        nv[c*4+2] = xv[c].z * inv * sv[c].z;
        nv[c*4+3] = xv[c].w * inv * sv[c].w;
    }
    #pragma unroll
    for (int c = 0; c < 4; c++) {
        ushort4 nb;
        nb.x = f2bf(nv[c*4+0]); nb.y = f2bf(nv[c*4+1]);
        nb.z = f2bf(nv[c*4+2]); nb.w = f2bf(nv[c*4+3]);
        *(ushort4*)(normed_bf + (size_t)t * H_ + h0 + c * 4) = nb;
    }

    float p[E_];
    #pragma unroll
    for (int e = 0; e < E_; e++) p[e] = 0.f;
    #pragma unroll
    for (int j = 0; j < 16; j++) {
        const float4* g4 = (const float4*)(gk + (size_t)(h0 + j) * E_);
        float4 a = g4[0], b = g4[1];
        float n = nv[j];
        p[0] += n*a.x; p[1] += n*a.y; p[2] += n*a.z; p[3] += n*a.w;
        p[4] += n*b.x; p[5] += n*b.y; p[6] += n*b.z; p[7] += n*b.w;
    }
    #pragma unroll
    for (int e = 0; e < E_; e++) {
        #pragma unroll
        for (int off = 32; off; off >>= 1) p[e] += __shfl_xor(p[e], off);
    }
    if (lane == 0) {
        int b0 = -1, b1 = -1; float l0 = -1e30f, l1 = -1e30f;
        #pragma unroll
        for (int e = 0; e < E_; e++) {
            float lg = p[e] + gb[e];
            if (lg > l0) { l1 = l0; b1 = b0; l0 = lg; b0 = e; }
            else if (lg > l1) { l1 = lg; b1 = e; }
        }
        float e1 = expf(l1 - l0);
        float w0 = 1.f / (1.f + e1);
        float w1 = e1 / (1.f + e1);
        int p0 = atomicAdd(&counts[b0], 1);
        tok_list[b0 * T_ + p0] = t * 2 + 0; w_list[b0 * T_ + p0] = w0;
        int p1 = atomicAdd(&counts[b1], 1);
        tok_list[b1 * T_ + p1] = t * 2 + 1; w_list[b1 * T_ + p1] = w1;
    }
}

// ---------------- Kernel 2: out = x (residual init) ------------------------
__global__ __launch_bounds__(256) void k_init_out(
    const float* __restrict__ x, float* __restrict__ out)
{
    size_t i = (size_t)blockIdx.x * 256 + threadIdx.x;
    ((float4*)out)[i] = ((const float4*)x)[i];
}

// ---------------- Kernel 3: GEMM1 64x64 tile, 2x2 wave grid, pipelined -----
template<bool PRE>
__global__ __launch_bounds__(256) void k_mlp1(
    const float* __restrict__ w1f, const unsigned short* __restrict__ w1b,
    const float* __restrict__ b1,
    const unsigned short* __restrict__ normed_bf,
    const int* __restrict__ counts, const int* __restrict__ tok_list,
    unsigned short* __restrict__ act)
{
    int e = blockIdx.z;
    int Ne = counts[e];
    int mt0 = blockIdx.y * 64;
    if (mt0 >= Ne) return;
    int it0 = blockIdx.x * 64;
    int tid = threadIdx.x;
    int lane = tid & 63, w = tid >> 6;
    int quad = lane >> 4, m16 = lane & 15;
    int wr = w >> 1, wc = w & 1;

    __shared__ unsigned short lA[64 * LDST];
    __shared__ unsigned short lBg[64 * LDST];
    __shared__ unsigned short lBl[64 * LDST];
    __shared__ int ls_tk[64];

    if (tid < 64) {
        int slot = mt0 + tid;
        ls_tk[tid] = (slot < Ne) ? tok_list[e * T_ + slot] : -1;
    }
    __syncthreads();

    f32x4 accg[2][2], accl[2][2];
    #pragma unroll
    for (int mi = 0; mi < 2; mi++)
        #pragma unroll
        for (int ni = 0; ni < 2; ni++) {
            accg[mi][ni] = (f32x4){0.f, 0.f, 0.f, 0.f};
            accl[mi][ni] = (f32x4){0.f, 0.f, 0.f, 0.f};
        }

    const size_t w1base = (size_t)e * 2 * I_ * H_;
    int rA = tid >> 3, sgA = tid & 7;      // A: 8 threads/row, 16B each
    int nB = tid >> 2, sgB = tid & 3;      // B: 4 threads/row, 16 elems each

    if (PRE) {
        // ---- pipelined path: load tile k into regs, write to LDS next iter
        int tk0 = ls_tk[rA], tk1 = ls_tk[rA + 32];
        const unsigned short* sA0 = normed_bf + (size_t)((tk0 < 0) ? 0 : (tk0 >> 1)) * H_ + sgA * 8;
        const unsigned short* sA1 = normed_bf + (size_t)((tk1 < 0) ? 0 : (tk1 >> 1)) * H_ + sgA * 8;
        const unsigned short* sG = w1b + w1base + (size_t)(it0 + nB) * H_ + sgB * 16;
        const unsigned short* sL = sG + (size_t)I_ * H_;

        uint4 ra0, ra1, rg0, rg1, rl0, rl1;
        ra0 = (tk0 >= 0) ? *(const uint4*)(sA0) : make_uint4(0,0,0,0);
        ra1 = (tk1 >= 0) ? *(const uint4*)(sA1) : make_uint4(0,0,0,0);
        rg0 = ((const uint4*)sG)[0]; rg1 = ((const uint4*)sG)[1];
        rl0 = ((const uint4*)sL)[0]; rl1 = ((const uint4*)sL)[1];

        for (int kk = 0; kk < H_; kk += 64) {
            __syncthreads();
            *(uint4*)(&lA[rA * LDST + sgA * 8])          = ra0;
            *(uint4*)(&lA[(rA + 32) * LDST + sgA * 8])   = ra1;
            *(uint4*)(&lBg[nB * LDST + sgB * 16])        = rg0;
            *(uint4*)(&lBg[nB * LDST + sgB * 16 + 8])    = rg1;
            *(uint4*)(&lBl[nB * LDST + sgB * 16])        = rl0;
            *(uint4*)(&lBl[nB * LDST + sgB * 16 + 8])    = rl1;
            __syncthreads();
            if (kk + 64 < H_) {
                int k2 = kk + 64;
                ra0 = (tk0 >= 0) ? *(const uint4*)(sA0 + k2) : make_uint4(0,0,0,0);
                ra1 = (tk1 >= 0) ? *(const uint4*)(sA1 + k2) : make_uint4(0,0,0,0);
                rg0 = ((const uint4*)(sG + k2))[0]; rg1 = ((const uint4*)(sG + k2))[1];
                rl0 = ((const uint4*)(sL + k2))[0]; rl1 = ((const uint4*)(sL + k2))[1];
            }
            #pragma unroll
            for (int ks = 0; ks < 64; ks += 32) {
                bf16x8 af[2], bg[2], bl[2];
                #pragma unroll
                for (int mi = 0; mi < 2; mi++)
                    af[mi] = *(const bf16x8*)(&lA[(wr * 32 + mi * 16 + m16) * LDST + ks + quad * 8]);
                #pragma unroll
                for (int ni = 0; ni < 2; ni++) {
                    bg[ni] = *(const bf16x8*)(&lBg[(wc * 32 + ni * 16 + m16) * LDST + ks + quad * 8]);
                    bl[ni] = *(const bf16x8*)(&lBl[(wc * 32 + ni * 16 + m16) * LDST + ks + quad * 8]);
                }
                #pragma unroll
                for (int mi = 0; mi < 2; mi++)
                    #pragma unroll
                    for (int ni = 0; ni < 2; ni++) {
                        accg[mi][ni] = __builtin_amdgcn_mfma_f32_16x16x32_bf16(
                            af[mi], bg[ni], accg[mi][ni], 0, 0, 0);
                        accl[mi][ni] = __builtin_amdgcn_mfma_f32_16x16x32_bf16(
                            af[mi], bl[ni], accl[mi][ni], 0, 0, 0);
                    }
            }
        }
    } else {
        // ---- fallback: round-6 structure with in-loop convert
        for (int kk = 0; kk < H_; kk += 64) {
            #pragma unroll
            for (int rr = 0; rr < 64; rr += 32) {
                int r = rA + rr;
                int tk = ls_tk[r];
                uint4 v = make_uint4(0u, 0u, 0u, 0u);
                if (tk >= 0)
                    v = *(const uint4*)(normed_bf + (size_t)(tk >> 1) * H_ + kk + sgA * 8);
                *(uint4*)(&lA[r * LDST + sgA * 8]) = v;
            }
            {
                const float* srcg = w1f + w1base + (size_t)(it0 + nB) * H_ + kk + sgB * 16;
                const float* srcl = srcg + (size_t)I_ * H_;
                unsigned short tg[16], tl[16];
                #pragma unroll
                for (int q = 0; q < 4; q++) {
                    float4 fg = ((const float4*)srcg)[q];
                    float4 fl = ((const float4*)srcl)[q];
                    tg[q*4+0] = f2bf(fg.x); tg[q*4+1] = f2bf(fg.y);
                    tg[q*4+2] = f2bf(fg.z); tg[q*4+3] = f2bf(fg.w);
                    tl[q*4+0] = f2bf(fl.x); tl[q*4+1] = f2bf(fl.y);
                    tl[q*4+2] = f2bf(fl.z); tl[q*4+3] = f2bf(fl.w);
                }
                *(uint4*)(&lBg[nB * LDST + sgB * 16])     = *(uint4*)(&tg[0]);
                *(uint4*)(&lBg[nB * LDST + sgB * 16 + 8]) = *(uint4*)(&tg[8]);
                *(uint4*)(&lBl[nB * LDST + sgB * 16])     = *(uint4*)(&tl[0]);
                *(uint4*)(&lBl[nB * LDST + sgB * 16 + 8]) = *(uint4*)(&tl[8]);
            }
            __syncthreads();
            #pragma unroll
            for (int ks = 0; ks < 64; ks += 32) {
                bf16x8 af[2], bg[2], bl[2];
                #pragma unroll
                for (int mi = 0; mi < 2; mi++)
                    af[mi] = *(const bf16x8*)(&lA[(wr * 32 + mi * 16 + m16) * LDST + ks + quad * 8]);
                #pragma unroll
                for (int ni = 0; ni < 2; ni++) {
                    bg[ni] = *(const bf16x8*)(&lBg[(wc * 32 + ni * 16 + m16) * LDST + ks + quad * 8]);
                    bl[ni] = *(const bf16x8*)(&lBl[(wc * 32 + ni * 16 + m16) * LDST + ks + quad * 8]);
                }
                #pragma unroll
                for (int mi = 0; mi < 2; mi++)
                    #pragma unroll
                    for (int ni = 0; ni < 2; ni++) {
                        accg[mi][ni] = __builtin_amdgcn_mfma_f32_16x16x32_bf16(
                            af[mi], bg[ni], accg[mi][ni], 0, 0, 0);
                        accl[mi][ni] = __builtin_amdgcn_mfma_f32_16x16x32_bf16(
                            af[mi], bl[ni], accl[mi][ni], 0, 0, 0);
                    }
            }
            __syncthreads();
        }
    }

    const float* b1g = b1 + (size_t)e * 2 * I_;
    const float* b1l = b1g + I_;
    #pragma unroll
    for (int mi = 0; mi < 2; mi++) {
        #pragma unroll
        for (int reg = 0; reg < 4; reg++) {
            int row = wr * 32 + mi * 16 + quad * 4 + reg;
            int tk = ls_tk[row];
            if (tk < 0) continue;
            #pragma unroll
            for (int ni = 0; ni < 2; ni++) {
                int i = it0 + wc * 32 + ni * 16 + m16;
                float g = accg[mi][ni][reg] + b1g[i];
                float l = accl[mi][ni][reg] + b1l[i];
                g = fminf(g, 7.f);
                l = fminf(fmaxf(l, -7.f), 7.f);
                float sw = g / (1.f + expf(-1.702f * g));
                act[(size_t)tk * I_ + i] = f2bf(sw * (l + 1.f));
            }
        }
    }
}

// ---------------- Kernel 4: GEMM2 64Mx128N, pipelined, scatter-add ---------
template<bool PRE>
__global__ __launch_bounds__(256) void k_mlp2(
    const float* __restrict__ w2f, const unsigned short* __restrict__ w2b,
    const float* __restrict__ b2,
    const unsigned short* __restrict__ act,
    const int* __restrict__ counts, const int* __restrict__ tok_list,
    const float* __restrict__ w_list,
    float* __restrict__ out)
{
    int e = blockIdx.z;
    int Ne = counts[e];
    int mt0 = blockIdx.y * 64;
    if (mt0 >= Ne) return;
    int ht0 = blockIdx.x * 128;
    int tid = threadIdx.x;
    int lane = tid & 63, w = tid >> 6;
    int quad = lane >> 4, m16 = lane & 15;
    int wr = w >> 1, wc = w & 1;

    __shared__ unsigned short lA[64 * LDST];
    __shared__ unsigned short lB[128 * LDST];
    __shared__ int ls_tk[64];
    __shared__ float ls_w[64];

    if (tid < 64) {
        int slot = mt0 + tid;
        ls_tk[tid] = (slot < Ne) ? tok_list[e * T_ + slot] : -1;
        ls_w[tid]  = (slot < Ne) ? w_list[e * T_ + slot] : 0.f;
    }
    __syncthreads();

    f32x4 acc[2][4];
    #pragma unroll
    for (int mi = 0; mi < 2; mi++)
        #pragma unroll
        for (int ni = 0; ni < 4; ni++)
            acc[mi][ni] = (f32x4){0.f, 0.f, 0.f, 0.f};

    const size_t w2base = (size_t)e * H_ * I_;
    int rA = tid >> 3, sgA = tid & 7;
    int nB = tid >> 2, sgB = tid & 3;

    if (PRE) {
        int tk0 = ls_tk[rA], tk1 = ls_tk[rA + 32];
        const unsigned short* sA0 = act + (size_t)((tk0 < 0) ? 0 : tk0) * I_ + sgA * 8;
        const unsigned short* sA1 = act + (size_t)((tk1 < 0) ? 0 : tk1) * I_ + sgA * 8;
        const unsigned short* sB0 = w2b + w2base + (size_t)(ht0 + nB) * I_ + sgB * 16;
        const unsigned short* sB1 = sB0 + (size_t)64 * I_;

        uint4 ra0, ra1, rb00, rb01, rb10, rb11;
        ra0 = (tk0 >= 0) ? *(const uint4*)(sA0) : make_uint4(0,0,0,0);
        ra1 = (tk1 >= 0) ? *(const uint4*)(sA1) : make_uint4(0,0,0,0);
        rb00 = ((const uint4*)sB0)[0]; rb01 = ((const uint4*)sB0)[1];
        rb10 = ((const uint4*)sB1)[0]; rb11 = ((const uint4*)sB1)[1];

        for (int kk = 0; kk < I_; kk += 64) {
            __syncthreads();
            *(uint4*)(&lA[rA * LDST + sgA * 8])            = ra0;
            *(uint4*)(&lA[(rA + 32) * LDST + sgA * 8])     = ra1;
            *(uint4*)(&lB[nB * LDST + sgB * 16])           = rb00;
            *(uint4*)(&lB[nB * LDST + sgB * 16 + 8])       = rb01;
            *(uint4*)(&lB[(nB + 64) * LDST + sgB * 16])    = rb10;
            *(uint4*)(&lB[(nB + 64) * LDST + sgB * 16 + 8])= rb11;
            __syncthreads();
            if (kk + 64 < I_) {
                int k2 = kk + 64;
                ra0 = (tk0 >= 0) ? *(const uint4*)(sA0 + k2) : make_uint4(0,0,0,0);
                ra1 = (tk1 >= 0) ? *(const uint4*)(sA1 + k2) : make_uint4(0,0,0,0);
                rb00 = ((const uint4*)(sB0 + k2))[0]; rb01 = ((const uint4*)(sB0 + k2))[1];
                rb10 = ((const uint4*)(sB1 + k2))[0]; rb11 = ((const uint4*)(sB1 + k2))[1];
            }
            #pragma unroll
            for (int ks = 0; ks < 64; ks += 32) {
                bf16x8 af[2], bf[4];
                #pragma unroll
                for (int mi = 0; mi < 2; mi++)
                    af[mi] = *(const bf16x8*)(&lA[(wr * 32 + mi * 16 + m16) * LDST + ks + quad * 8]);
                #pragma unroll
                for (int ni = 0; ni < 4; ni++)
                    bf[ni] = *(const bf16x8*)(&lB[(wc * 64 + ni * 16 + m16) * LDST + ks + quad * 8]);
                #pragma unroll
                for (int mi = 0; mi < 2; mi++)
                    #pragma unroll
                    for (int ni = 0; ni < 4; ni++)
                        acc[mi][ni] = __builtin_amdgcn_mfma_f32_16x16x32_bf16(
                            af[mi], bf[ni], acc[mi][ni], 0, 0, 0);
            }
        }
    } else {
        for (int kk = 0; kk < I_; kk += 64) {
            #pragma unroll
            for (int rr = 0; rr < 64; rr += 32) {
                int r = rA + rr;
                int tk = ls_tk[r];
                uint4 v = make_uint4(0u, 0u, 0u, 0u);
                if (tk >= 0)
                    v = *(const uint4*)(act + (size_t)tk * I_ + kk + sgA * 8);
                *(uint4*)(&lA[r * LDST + sgA * 8]) = v;
            }
            #pragma unroll
            for (int rr = 0; rr < 128; rr += 64) {
                int r = nB + rr;
                const float* src = w2f + w2base + (size_t)(ht0 + r) * I_ + kk + sgB * 16;
                unsigned short tb[16];
                #pragma unroll
                for (int q = 0; q < 4; q++) {
                    float4 f4 = ((const float4*)src)[q];
                    tb[q*4+0] = f2bf(f4.x); tb[q*4+1] = f2bf(f4.y);
                    tb[q*4+2] = f2bf(f4.z); tb[q*4+3] = f2bf(f4.w);
                }
                *(uint4*)(&lB[r * LDST + sgB * 16])     = *(uint4*)(&tb[0]);
                *(uint4*)(&lB[r * LDST + sgB * 16 + 8]) = *(uint4*)(&tb[8]);
            }
            __syncthreads();
            #pragma unroll
            for (int ks = 0; ks < 64; ks += 32) {
                bf16x8 af[2], bf[4];
                #pragma unroll
                for (int mi = 0; mi < 2; mi++)
                    af[mi] = *(const bf16x8*)(&lA[(wr * 32 + mi * 16 + m16) * LDST + ks + quad * 8]);
                #pragma unroll
                for (int ni = 0; ni < 4; ni++)
                    bf[ni] = *(const bf16x8*)(&lB[(wc * 64 + ni * 16 + m16) * LDST + ks + quad * 8]);
                #pragma unroll
                for (int mi = 0; mi < 2; mi++)
                    #pragma unroll
                    for (int ni = 0; ni < 4; ni++)
                        acc[mi][ni] = __builtin_amdgcn_mfma_f32_16x16x32_bf16(
                            af[mi], bf[ni], acc[mi][ni], 0, 0, 0);
            }
            __syncthreads();
        }
    }

    const float* b2e = b2 + (size_t)e * H_;
    #pragma unroll
    for (int mi = 0; mi < 2; mi++) {
        #pragma unroll
        for (int reg = 0; reg < 4; reg++) {
            int row = wr * 32 + mi * 16 + quad * 4 + reg;
            int tk = ls_tk[row];
            if (tk < 0) continue;
            int t = tk >> 1;
            float wgt = ls_w[row];
            #pragma unroll
            for (int ni = 0; ni < 4; ni++) {
                int h = ht0 + wc * 64 + ni * 16 + m16;
                float v = acc[mi][ni][reg] + b2e[h];
                atomicAdd(&out[(size_t)t * H_ + h], wgt * v);
            }
        }
    }
}

// ---------------- launcher -------------------------------------------------
extern "C" void kernel_launch(void* const* d_in, const int* in_sizes, int n_in,
                              void* d_out, int out_size, void* d_ws, size_t ws_size,
                              hipStream_t stream) {
    const float* x     = (const float*)d_in[0];
    const float* scale = (const float*)d_in[1];
    const float* gk    = (const float*)d_in[2];
    const float* gb    = (const float*)d_in[3];
    const float* w1    = (const float*)d_in[4];
    const float* b1    = (const float*)d_in[5];
    const float* w2    = (const float*)d_in[6];
    const float* b2    = (const float*)d_in[7];
    float* out = (float*)d_out;

    char* ws = (char*)d_ws;
    const size_t MB = 1024 * 1024;
    bool pre = ws_size >= (size_t)138 * MB;

    unsigned short* normed_bf = (unsigned short*)ws;                    // 8 MB
    unsigned short* act       = (unsigned short*)(ws + 8 * MB);         // 32 MB
    unsigned short* w1b = nullptr;
    unsigned short* w2b = nullptr;
    char* ctl;
    if (pre) {
        w1b = (unsigned short*)(ws + 40 * MB);    // 64 MB
        w2b = (unsigned short*)(ws + 104 * MB);   // 32 MB
        ctl = ws + 136 * MB;
    } else {
        ctl = ws + 40 * MB;
    }
    int*   counts   = (int*)ctl;
    int*   tok_list = (int*)(ctl + 256);
    float* w_list   = (float*)(ctl + 256 + (size_t)E_ * T_ * 4);

    hipMemsetAsync(counts, 0, E_ * sizeof(int), stream);

    k_norm_gate<<<dim3(T_ / 4), dim3(256), 0, stream>>>(x, scale, gk, gb,
                                                        normed_bf, counts, tok_list, w_list);
    if (pre) {
        k_convert<<<dim3((E_ * 2 * I_ * H_) / (256 * 8)), dim3(256), 0, stream>>>(w1, w1b);
        k_convert<<<dim3((E_ * H_ * I_) / (256 * 8)), dim3(256), 0, stream>>>(w2, w2b);
    }
    k_init_out<<<dim3(T_ * H_ / (256 * 4)), dim3(256), 0, stream>>>(x, out);

    if (pre) {
        k_mlp1<true><<<dim3(I_ / 64, T_ / 64, E_), dim3(256), 0, stream>>>(
            nullptr, w1b, b1, normed_bf, counts, tok_list, act);
        k_mlp2<true><<<dim3(H_ / 128, T_ / 64, E_), dim3(256), 0, stream>>>(
            nullptr, w2b, b2, act, counts, tok_list, w_list, out);
    } else {
        k_mlp1<false><<<dim3(I_ / 64, T_ / 64, E_), dim3(256), 0, stream>>>(
            w1, nullptr, b1, normed_bf, counts, tok_list, act);
        k_mlp2<false><<<dim3(H_ / 128, T_ / 64, E_), dim3(256), 0, stream>>>(
            w2, nullptr, b2, act, counts, tok_list, w_list, out);
    }
}

// Round 8
// 567.545 us; speedup vs baseline: 1.8528x; 1.0568x over previous
//
#include <hip/hip_runtime.h>
#include <hip/hip_bf16.h>
#include <math.h>

#define T_ 4096
#define H_ 1024
#define E_ 8
#define I_ 2048
#define EPS_ 1e-5f

using bf16x8 = __attribute__((ext_vector_type(8))) short;
using f32x4  = __attribute__((ext_vector_type(4))) float;

static __device__ __forceinline__ unsigned short f2bf(float f) {
    union { float f; unsigned int u; } v; v.f = f;
    unsigned int u = v.u;
    u += 0x7fffu + ((u >> 16) & 1u);   // RNE
    return (unsigned short)(u >> 16);
}

// ---------------- Kernel 0: fp32 -> bf16 weight preconvert -----------------
__global__ __launch_bounds__(256) void k_convert(
    const float* __restrict__ src, unsigned short* __restrict__ dst)
{
    size_t i = (size_t)blockIdx.x * 256 + threadIdx.x;
    const float4* s = (const float4*)src + i * 2;
    float4 a = s[0], b = s[1];
    ushort4 lo, hi;
    lo.x = f2bf(a.x); lo.y = f2bf(a.y); lo.z = f2bf(a.z); lo.w = f2bf(a.w);
    hi.x = f2bf(b.x); hi.y = f2bf(b.y); hi.z = f2bf(b.z); hi.w = f2bf(b.w);
    ((ushort4*)dst)[i * 2]     = lo;
    ((ushort4*)dst)[i * 2 + 1] = hi;
}

// ---------------- Kernel 1: RMSNorm + gating, one wave per token -----------
__global__ __launch_bounds__(256) void k_norm_gate(
    const float* __restrict__ x, const float* __restrict__ scale,
    const float* __restrict__ gk, const float* __restrict__ gb,
    unsigned short* __restrict__ normed_bf,
    int* __restrict__ counts, int* __restrict__ tok_list, float* __restrict__ wtok)
{
    int tid = threadIdx.x;
    int wave = tid >> 6, lane = tid & 63;
    int t = blockIdx.x * 4 + wave;
    const float* xr = x + (size_t)t * H_;
    int h0 = lane * 16;

    float4 xv[4], sv[4];
    #pragma unroll
    for (int c = 0; c < 4; c++) {
        xv[c] = *(const float4*)(xr + h0 + c * 4);
        sv[c] = *(const float4*)(scale + h0 + c * 4);
    }
    float ss = 0.f;
    #pragma unroll
    for (int c = 0; c < 4; c++)
        ss += xv[c].x*xv[c].x + xv[c].y*xv[c].y + xv[c].z*xv[c].z + xv[c].w*xv[c].w;
    #pragma unroll
    for (int off = 32; off; off >>= 1) ss += __shfl_xor(ss, off);
    float inv = 1.0f / sqrtf(ss / (float)H_ + EPS_);

    float nv[16];
    #pragma unroll
    for (int c = 0; c < 4; c++) {
        nv[c*4+0] = xv[c].x * inv * sv[c].x;
        nv[c*4+1] = xv[c].y * inv * sv[c].y;
        nv[c*4+2] = xv[c].z * inv * sv[c].z;
        nv[c*4+3] = xv[c].w * inv * sv[c].w;
    }
    #pragma unroll
    for (int c = 0; c < 4; c++) {
        ushort4 nb;
        nb.x = f2bf(nv[c*4+0]); nb.y = f2bf(nv[c*4+1]);
        nb.z = f2bf(nv[c*4+2]); nb.w = f2bf(nv[c*4+3]);
        *(ushort4*)(normed_bf + (size_t)t * H_ + h0 + c * 4) = nb;
    }

    float p[E_];
    #pragma unroll
    for (int e = 0; e < E_; e++) p[e] = 0.f;
    #pragma unroll
    for (int j = 0; j < 16; j++) {
        const float4* g4 = (const float4*)(gk + (size_t)(h0 + j) * E_);
        float4 a = g4[0], b = g4[1];
        float n = nv[j];
        p[0] += n*a.x; p[1] += n*a.y; p[2] += n*a.z; p[3] += n*a.w;
        p[4] += n*b.x; p[5] += n*b.y; p[6] += n*b.z; p[7] += n*b.w;
    }
    #pragma unroll
    for (int e = 0; e < E_; e++) {
        #pragma unroll
        for (int off = 32; off; off >>= 1) p[e] += __shfl_xor(p[e], off);
    }
    if (lane == 0) {
        int b0 = -1, b1 = -1; float l0 = -1e30f, l1 = -1e30f;
        #pragma unroll
        for (int e = 0; e < E_; e++) {
            float lg = p[e] + gb[e];
            if (lg > l0) { l1 = l0; b1 = b0; l0 = lg; b0 = e; }
            else if (lg > l1) { l1 = lg; b1 = e; }
        }
        float e1 = expf(l1 - l0);
        float w0 = 1.f / (1.f + e1);
        float w1 = e1 / (1.f + e1);
        wtok[t * 2 + 0] = w0;
        wtok[t * 2 + 1] = w1;
        int p0 = atomicAdd(&counts[b0], 1);
        tok_list[b0 * T_ + p0] = t * 2 + 0;
        int p1 = atomicAdd(&counts[b1], 1);
        tok_list[b1 * T_ + p1] = t * 2 + 1;
    }
}

// ---------------- Kernel 3: GEMM1 64x64 tile, swizzled LDS, pipelined ------
// LDS row = 64 elems (no pad); 16B chunk j stored at physical chunk j^(row&7).
__global__ __launch_bounds__(256) void k_mlp1(
    const unsigned short* __restrict__ w1b,
    const float* __restrict__ b1,
    const unsigned short* __restrict__ normed_bf,
    const int* __restrict__ counts, const int* __restrict__ tok_list,
    unsigned short* __restrict__ act)
{
    int e = blockIdx.z;
    int Ne = counts[e];
    int mt0 = blockIdx.y * 64;
    if (mt0 >= Ne) return;
    int it0 = blockIdx.x * 64;
    int tid = threadIdx.x;
    int lane = tid & 63, w = tid >> 6;
    int quad = lane >> 4, m16 = lane & 15;
    int wr = w >> 1, wc = w & 1;

    __shared__ unsigned short lA[64 * 64];
    __shared__ unsigned short lBg[64 * 64];
    __shared__ unsigned short lBl[64 * 64];
    __shared__ int ls_tk[64];

    if (tid < 64) {
        int slot = mt0 + tid;
        ls_tk[tid] = (slot < Ne) ? tok_list[e * T_ + slot] : -1;
    }
    __syncthreads();

    f32x4 accg[2][2], accl[2][2];
    #pragma unroll
    for (int mi = 0; mi < 2; mi++)
        #pragma unroll
        for (int ni = 0; ni < 2; ni++) {
            accg[mi][ni] = (f32x4){0.f, 0.f, 0.f, 0.f};
            accl[mi][ni] = (f32x4){0.f, 0.f, 0.f, 0.f};
        }

    const size_t w1base = (size_t)e * 2 * I_ * H_;
    int rA = tid >> 3, sgA = tid & 7;      // A: rows rA, rA+32; 16B each
    int nB = tid >> 2, sgB = tid & 3;      // B: row nB; 32B each
    int jA = sgA ^ (rA & 7);               // (rA+32)&7 == rA&7
    int jB0 = (2 * sgB) ^ (nB & 7);
    int jB1 = (2 * sgB + 1) ^ (nB & 7);

    int tk0 = ls_tk[rA], tk1 = ls_tk[rA + 32];
    const unsigned short* sA0 = normed_bf + (size_t)((tk0 < 0) ? 0 : (tk0 >> 1)) * H_ + sgA * 8;
    const unsigned short* sA1 = normed_bf + (size_t)((tk1 < 0) ? 0 : (tk1 >> 1)) * H_ + sgA * 8;
    const unsigned short* sG = w1b + w1base + (size_t)(it0 + nB) * H_ + sgB * 16;
    const unsigned short* sL = sG + (size_t)I_ * H_;

    uint4 ra0, ra1, rg0, rg1, rl0, rl1;
    ra0 = (tk0 >= 0) ? *(const uint4*)(sA0) : make_uint4(0,0,0,0);
    ra1 = (tk1 >= 0) ? *(const uint4*)(sA1) : make_uint4(0,0,0,0);
    rg0 = ((const uint4*)sG)[0]; rg1 = ((const uint4*)sG)[1];
    rl0 = ((const uint4*)sL)[0]; rl1 = ((const uint4*)sL)[1];

    for (int kk = 0; kk < H_; kk += 64) {
        __syncthreads();
        *(uint4*)(&lA[rA * 64 + jA * 8])          = ra0;
        *(uint4*)(&lA[(rA + 32) * 64 + jA * 8])   = ra1;
        *(uint4*)(&lBg[nB * 64 + jB0 * 8])        = rg0;
        *(uint4*)(&lBg[nB * 64 + jB1 * 8])        = rg1;
        *(uint4*)(&lBl[nB * 64 + jB0 * 8])        = rl0;
        *(uint4*)(&lBl[nB * 64 + jB1 * 8])        = rl1;
        __syncthreads();
        if (kk + 64 < H_) {
            int k2 = kk + 64;
            ra0 = (tk0 >= 0) ? *(const uint4*)(sA0 + k2) : make_uint4(0,0,0,0);
            ra1 = (tk1 >= 0) ? *(const uint4*)(sA1 + k2) : make_uint4(0,0,0,0);
            rg0 = ((const uint4*)(sG + k2))[0]; rg1 = ((const uint4*)(sG + k2))[1];
            rl0 = ((const uint4*)(sL + k2))[0]; rl1 = ((const uint4*)(sL + k2))[1];
        }
        #pragma unroll
        for (int ks2 = 0; ks2 < 2; ks2++) {
            int jj = ks2 * 4 + quad;
            int m7 = m16 & 7;
            bf16x8 af[2], bg[2], bl[2];
            #pragma unroll
            for (int mi = 0; mi < 2; mi++)
                af[mi] = *(const bf16x8*)(&lA[(wr * 32 + mi * 16 + m16) * 64 + (jj ^ m7) * 8]);
            #pragma unroll
            for (int ni = 0; ni < 2; ni++) {
                bg[ni] = *(const bf16x8*)(&lBg[(wc * 32 + ni * 16 + m16) * 64 + (jj ^ m7) * 8]);
                bl[ni] = *(const bf16x8*)(&lBl[(wc * 32 + ni * 16 + m16) * 64 + (jj ^ m7) * 8]);
            }
            #pragma unroll
            for (int mi = 0; mi < 2; mi++)
                #pragma unroll
                for (int ni = 0; ni < 2; ni++) {
                    accg[mi][ni] = __builtin_amdgcn_mfma_f32_16x16x32_bf16(
                        af[mi], bg[ni], accg[mi][ni], 0, 0, 0);
                    accl[mi][ni] = __builtin_amdgcn_mfma_f32_16x16x32_bf16(
                        af[mi], bl[ni], accl[mi][ni], 0, 0, 0);
                }
        }
    }

    const float* b1g = b1 + (size_t)e * 2 * I_;
    const float* b1l = b1g + I_;
    #pragma unroll
    for (int mi = 0; mi < 2; mi++) {
        #pragma unroll
        for (int reg = 0; reg < 4; reg++) {
            int row = wr * 32 + mi * 16 + quad * 4 + reg;
            int tk = ls_tk[row];
            if (tk < 0) continue;
            #pragma unroll
            for (int ni = 0; ni < 2; ni++) {
                int i = it0 + wc * 32 + ni * 16 + m16;
                float g = accg[mi][ni][reg] + b1g[i];
                float l = accl[mi][ni][reg] + b1l[i];
                g = fminf(g, 7.f);
                l = fminf(fmaxf(l, -7.f), 7.f);
                float sw = g / (1.f + expf(-1.702f * g));
                act[(size_t)tk * I_ + i] = f2bf(sw * (l + 1.f));
            }
        }
    }
}

// ---------------- Kernel 4: GEMM2 64Mx128N, swizzled, stores to ybuf -------
__global__ __launch_bounds__(256) void k_mlp2(
    const unsigned short* __restrict__ w2b,
    const float* __restrict__ b2,
    const unsigned short* __restrict__ act,
    const int* __restrict__ counts, const int* __restrict__ tok_list,
    float* __restrict__ ybuf)
{
    int e = blockIdx.z;
    int Ne = counts[e];
    int mt0 = blockIdx.y * 64;
    if (mt0 >= Ne) return;
    int ht0 = blockIdx.x * 128;
    int tid = threadIdx.x;
    int lane = tid & 63, w = tid >> 6;
    int quad = lane >> 4, m16 = lane & 15;
    int wr = w >> 1, wc = w & 1;

    __shared__ unsigned short lA[64 * 64];
    __shared__ unsigned short lB[128 * 64];
    __shared__ int ls_tk[64];

    if (tid < 64) {
        int slot = mt0 + tid;
        ls_tk[tid] = (slot < Ne) ? tok_list[e * T_ + slot] : -1;
    }
    __syncthreads();

    f32x4 acc[2][4];
    #pragma unroll
    for (int mi = 0; mi < 2; mi++)
        #pragma unroll
        for (int ni = 0; ni < 4; ni++)
            acc[mi][ni] = (f32x4){0.f, 0.f, 0.f, 0.f};

    const size_t w2base = (size_t)e * H_ * I_;
    int rA = tid >> 3, sgA = tid & 7;
    int nB = tid >> 2, sgB = tid & 3;
    int jA = sgA ^ (rA & 7);
    int jB0 = (2 * sgB) ^ (nB & 7);
    int jB1 = (2 * sgB + 1) ^ (nB & 7);

    int tk0 = ls_tk[rA], tk1 = ls_tk[rA + 32];
    const unsigned short* sA0 = act + (size_t)((tk0 < 0) ? 0 : tk0) * I_ + sgA * 8;
    const unsigned short* sA1 = act + (size_t)((tk1 < 0) ? 0 : tk1) * I_ + sgA * 8;
    const unsigned short* sB0 = w2b + w2base + (size_t)(ht0 + nB) * I_ + sgB * 16;
    const unsigned short* sB1 = sB0 + (size_t)64 * I_;

    uint4 ra0, ra1, rb00, rb01, rb10, rb11;
    ra0 = (tk0 >= 0) ? *(const uint4*)(sA0) : make_uint4(0,0,0,0);
    ra1 = (tk1 >= 0) ? *(const uint4*)(sA1) : make_uint4(0,0,0,0);
    rb00 = ((const uint4*)sB0)[0]; rb01 = ((const uint4*)sB0)[1];
    rb10 = ((const uint4*)sB1)[0]; rb11 = ((const uint4*)sB1)[1];

    for (int kk = 0; kk < I_; kk += 64) {
        __syncthreads();
        *(uint4*)(&lA[rA * 64 + jA * 8])               = ra0;
        *(uint4*)(&lA[(rA + 32) * 64 + jA * 8])        = ra1;
        *(uint4*)(&lB[nB * 64 + jB0 * 8])              = rb00;
        *(uint4*)(&lB[nB * 64 + jB1 * 8])              = rb01;
        *(uint4*)(&lB[(nB + 64) * 64 + jB0 * 8])       = rb10;
        *(uint4*)(&lB[(nB + 64) * 64 + jB1 * 8])       = rb11;
        __syncthreads();
        if (kk + 64 < I_) {
            int k2 = kk + 64;
            ra0 = (tk0 >= 0) ? *(const uint4*)(sA0 + k2) : make_uint4(0,0,0,0);
            ra1 = (tk1 >= 0) ? *(const uint4*)(sA1 + k2) : make_uint4(0,0,0,0);
            rb00 = ((const uint4*)(sB0 + k2))[0]; rb01 = ((const uint4*)(sB0 + k2))[1];
            rb10 = ((const uint4*)(sB1 + k2))[0]; rb11 = ((const uint4*)(sB1 + k2))[1];
        }
        #pragma unroll
        for (int ks2 = 0; ks2 < 2; ks2++) {
            int jj = ks2 * 4 + quad;
            int m7 = m16 & 7;
            bf16x8 af[2], bf[4];
            #pragma unroll
            for (int mi = 0; mi < 2; mi++)
                af[mi] = *(const bf16x8*)(&lA[(wr * 32 + mi * 16 + m16) * 64 + (jj ^ m7) * 8]);
            #pragma unroll
            for (int ni = 0; ni < 4; ni++)
                bf[ni] = *(const bf16x8*)(&lB[(wc * 64 + ni * 16 + m16) * 64 + (jj ^ m7) * 8]);
            #pragma unroll
            for (int mi = 0; mi < 2; mi++)
                #pragma unroll
                for (int ni = 0; ni < 4; ni++)
                    acc[mi][ni] = __builtin_amdgcn_mfma_f32_16x16x32_bf16(
                        af[mi], bf[ni], acc[mi][ni], 0, 0, 0);
        }
    }

    const float* b2e = b2 + (size_t)e * H_;
    #pragma unroll
    for (int mi = 0; mi < 2; mi++) {
        #pragma unroll
        for (int reg = 0; reg < 4; reg++) {
            int row = wr * 32 + mi * 16 + quad * 4 + reg;
            int tk = ls_tk[row];
            if (tk < 0) continue;
            #pragma unroll
            for (int ni = 0; ni < 4; ni++) {
                int h = ht0 + wc * 64 + ni * 16 + m16;
                ybuf[(size_t)tk * H_ + h] = acc[mi][ni][reg] + b2e[h];
            }
        }
    }
}

// ---------------- Kernel 5: out = x + w0*y0 + w1*y1 ------------------------
__global__ __launch_bounds__(256) void k_combine(
    const float* __restrict__ x, const float* __restrict__ ybuf,
    const float* __restrict__ wtok, float* __restrict__ out)
{
    int t = blockIdx.x;
    int tid = threadIdx.x;
    float w0 = wtok[t * 2 + 0];
    float w1 = wtok[t * 2 + 1];
    float4 xv = ((const float4*)(x + (size_t)t * H_))[tid];
    float4 y0 = ((const float4*)(ybuf + (size_t)(t * 2) * H_))[tid];
    float4 y1 = ((const float4*)(ybuf + (size_t)(t * 2 + 1) * H_))[tid];
    float4 o;
    o.x = xv.x + w0 * y0.x + w1 * y1.x;
    o.y = xv.y + w0 * y0.y + w1 * y1.y;
    o.z = xv.z + w0 * y0.z + w1 * y1.z;
    o.w = xv.w + w0 * y0.w + w1 * y1.w;
    ((float4*)(out + (size_t)t * H_))[tid] = o;
}

// ---------------- launcher -------------------------------------------------
extern "C" void kernel_launch(void* const* d_in, const int* in_sizes, int n_in,
                              void* d_out, int out_size, void* d_ws, size_t ws_size,
                              hipStream_t stream) {
    const float* x     = (const float*)d_in[0];
    const float* scale = (const float*)d_in[1];
    const float* gk    = (const float*)d_in[2];
    const float* gb    = (const float*)d_in[3];
    const float* w1    = (const float*)d_in[4];
    const float* b1    = (const float*)d_in[5];
    const float* w2    = (const float*)d_in[6];
    const float* b2    = (const float*)d_in[7];
    float* out = (float*)d_out;

    char* ws = (char*)d_ws;
    const size_t MB = 1024 * 1024;
    unsigned short* normed_bf = (unsigned short*)ws;                  // 8 MB
    unsigned short* act       = (unsigned short*)(ws + 8 * MB);       // 32 MB
    unsigned short* w1b       = (unsigned short*)(ws + 40 * MB);      // 64 MB
    float*          ybuf      = (float*)(ws + 40 * MB);               // 32 MB, aliases w1b (dead after k_mlp1)
    unsigned short* w2b       = (unsigned short*)(ws + 104 * MB);     // 32 MB
    char* ctl                 = ws + 136 * MB;
    int*   counts   = (int*)ctl;                                      // 256 B pad
    int*   tok_list = (int*)(ctl + 256);                              // E*T*4 = 128 KB
    float* wtok     = (float*)(ctl + 256 + (size_t)E_ * T_ * 4);      // 2T*4 = 32 KB

    hipMemsetAsync(counts, 0, E_ * sizeof(int), stream);

    k_norm_gate<<<dim3(T_ / 4), dim3(256), 0, stream>>>(
        x, scale, gk, gb, normed_bf, counts, tok_list, wtok);
    k_convert<<<dim3((E_ * 2 * I_ * H_) / (256 * 8)), dim3(256), 0, stream>>>(w1, w1b);
    k_convert<<<dim3((E_ * H_ * I_) / (256 * 8)), dim3(256), 0, stream>>>(w2, w2b);

    k_mlp1<<<dim3(I_ / 64, T_ / 64, E_), dim3(256), 0, stream>>>(
        w1b, b1, normed_bf, counts, tok_list, act);
    k_mlp2<<<dim3(H_ / 128, T_ / 64, E_), dim3(256), 0, stream>>>(
        w2b, b2, act, counts, tok_list, ybuf);
    k_combine<<<dim3(T_), dim3(256), 0, stream>>>(x, ybuf, wtok, out);
}